// Round 1
// baseline (1331.711 us; speedup 1.0000x reference)
//
#include <hip/hip_runtime.h>
#include <hip/hip_bf16.h>
#include <math.h>

// GraphGather: segment_sum + segment_max over sorted membership, then tanh.
// atom_features: fp32 [1048576, 256]; membership: int32 [1048576] (sorted);
// out: fp32 [4096, 512] = tanh([sum | max]).
//
// One block per segment. Membership is sorted -> each segment is a contiguous
// run found by binary search (no atomics, no workspace). 4 waves/block each
// take one atom row per iteration; each lane loads a float4 (coalesced 1 KiB
// per wave-instruction). Register accumulators, LDS cross-wave combine.

constexpr int kNAtoms = 1048576;
constexpr int kDFeat  = 256;
constexpr int kBatch  = 4096;

__global__ __launch_bounds__(256) void graph_gather_kernel(
    const float* __restrict__ feats,
    const int*   __restrict__ mem,
    float*       __restrict__ out)
{
    const int seg  = blockIdx.x;
    const int tid  = threadIdx.x;
    const int lane = tid & 63;   // which float4 within a 256-float row
    const int wv   = tid >> 6;   // wave id, 0..3

    // --- segment bounds via binary search (sorted membership) ---
    __shared__ int s_bounds[2];
    if (tid < 2) {
        const int target = seg + tid;         // lower_bound(seg), lower_bound(seg+1)
        int lo = 0, hi = kNAtoms;
        while (lo < hi) {
            const int mid = (lo + hi) >> 1;
            if (mem[mid] < target) lo = mid + 1; else hi = mid;
        }
        s_bounds[tid] = lo;
    }
    __syncthreads();
    const int start = s_bounds[0];
    const int end   = s_bounds[1];

    // --- main accumulation: wave w takes atoms start+w, start+w+4, ... ---
    float4 sum = make_float4(0.f, 0.f, 0.f, 0.f);
    float4 mx  = make_float4(-INFINITY, -INFINITY, -INFINITY, -INFINITY);

    const float* base = feats + (size_t)lane * 4;
    for (int a = start + wv; a < end; a += 4) {
        const float4 v = *reinterpret_cast<const float4*>(base + (size_t)a * kDFeat);
        sum.x += v.x; sum.y += v.y; sum.z += v.z; sum.w += v.w;
        mx.x = fmaxf(mx.x, v.x); mx.y = fmaxf(mx.y, v.y);
        mx.z = fmaxf(mx.z, v.z); mx.w = fmaxf(mx.w, v.w);
    }

    // --- cross-wave combine via LDS (4 waves x 64 lanes x float4 = 4 KB each) ---
    __shared__ float4 s_sum[4][64];
    __shared__ float4 s_max[4][64];
    s_sum[wv][lane] = sum;
    s_max[wv][lane] = mx;
    __syncthreads();

    if (wv == 0) {
        #pragma unroll
        for (int i = 1; i < 4; ++i) {
            const float4 a = s_sum[i][lane];
            sum.x += a.x; sum.y += a.y; sum.z += a.z; sum.w += a.w;
            const float4 b = s_max[i][lane];
            mx.x = fmaxf(mx.x, b.x); mx.y = fmaxf(mx.y, b.y);
            mx.z = fmaxf(mx.z, b.z); mx.w = fmaxf(mx.w, b.w);
        }
        const float4 osum = make_float4(tanhf(sum.x), tanhf(sum.y),
                                        tanhf(sum.z), tanhf(sum.w));
        const float4 omax = make_float4(tanhf(mx.x), tanhf(mx.y),
                                        tanhf(mx.z), tanhf(mx.w));
        float* o = out + (size_t)seg * (2 * kDFeat);
        *reinterpret_cast<float4*>(o + lane * 4)          = osum;
        *reinterpret_cast<float4*>(o + kDFeat + lane * 4) = omax;
    }
}

extern "C" void kernel_launch(void* const* d_in, const int* in_sizes, int n_in,
                              void* d_out, int out_size, void* d_ws, size_t ws_size,
                              hipStream_t stream) {
    const float* feats = (const float*)d_in[0];   // [1048576, 256] fp32
    const int*   mem   = (const int*)d_in[1];     // [1048576] int32, sorted
    float*       out   = (float*)d_out;           // [4096, 512] fp32

    graph_gather_kernel<<<kBatch, 256, 0, stream>>>(feats, mem, out);
}